// Round 1
// baseline (192.844 us; speedup 1.0000x reference)
//
#include <hip/hip_runtime.h>
#include <hip/hip_bf16.h>
#include <math.h>

#define PI_F 3.14159265358979323846f

// ---------------------------------------------------------------------------
// Kernel 1: build the fixed 64x64 complex unitary U (everything after the
// input RY layer). One block per basis state (64 blocks x 64 threads = 1 wave).
// Lane l holds amplitude of flat index l. Qubit q <-> bit (5-q).
// Output layout: U2[(k*64 + j)*2 + {0,1}] = {Re,Im} of U[k][j]  (k = out idx,
// j = input basis idx) so the main kernel reads 128 contiguous floats per k.
// ---------------------------------------------------------------------------
__global__ __launch_bounds__(64) void build_u(const float* __restrict__ qw,
                                              float* __restrict__ U2) {
    const int l = threadIdx.x;   // amplitude index (0..63)
    const int b = blockIdx.x;    // input basis state (0..63)

    float ar = (l == b) ? 1.0f : 0.0f;
    float ai = 0.0f;

    // Phase 2: for i: RX(qw[0][i], i) ; RZ(qw[1][i], i)
    #pragma unroll
    for (int i = 0; i < 6; ++i) {
        const int mask = 1 << (5 - i);
        // RX: new = c*amp - i*s*partner  (same form for both bit values)
        float th = 0.5f * qw[0 * 6 + i];
        float c = cosf(th), sn = sinf(th);
        float pr = __shfl_xor(ar, mask);
        float pi = __shfl_xor(ai, mask);
        float nr = c * ar + sn * pi;
        float ni = c * ai - sn * pr;
        ar = nr; ai = ni;
        // RZ: bit0 *= e^{-i th}, bit1 *= e^{+i th}
        th = 0.5f * qw[1 * 6 + i];
        c = cosf(th); sn = sinf(th);
        float zn = (l & mask) ? 1.0f : -1.0f;
        nr = c * ar - zn * sn * ai;
        ni = c * ai + zn * sn * ar;
        ar = nr; ai = ni;
    }

    // CNOT ring: (0,1),(1,2),(2,3),(3,4),(4,5),(5,0) in order
    #pragma unroll
    for (int i = 0; i < 6; ++i) {
        const int ctrl = i, tgt = (i + 1) % 6;
        const int cm = 1 << (5 - ctrl), tm = 1 << (5 - tgt);
        float pr = __shfl_xor(ar, tm);
        float pi = __shfl_xor(ai, tm);
        bool take = (l & cm) != 0;
        ar = take ? pr : ar;
        ai = take ? pi : ai;
    }

    // Phase 4: for i: RY(qw[2][i], i) ; RZ(qw[3][i], i)
    #pragma unroll
    for (int i = 0; i < 6; ++i) {
        const int mask = 1 << (5 - i);
        // RY: bit0: c*s0 - s*s1 ; bit1: s*s0 + c*s1
        float th = 0.5f * qw[2 * 6 + i];
        float c = cosf(th), sn = sinf(th);
        float pr = __shfl_xor(ar, mask);
        float pi = __shfl_xor(ai, mask);
        float sg = (l & mask) ? sn : -sn;
        float nr = c * ar + sg * pr;
        float ni = c * ai + sg * pi;
        ar = nr; ai = ni;
        // RZ
        th = 0.5f * qw[3 * 6 + i];
        c = cosf(th); sn = sinf(th);
        float zn = (l & mask) ? 1.0f : -1.0f;
        nr = c * ar - zn * sn * ai;
        ni = c * ai + zn * sn * ar;
        ar = nr; ai = ni;
    }

    // CNOTs (0,1),(2,3),(4,5)
    #pragma unroll
    for (int i = 0; i < 6; i += 2) {
        const int cm = 1 << (5 - i), tm = 1 << (5 - (i + 1));
        float pr = __shfl_xor(ar, tm);
        float pi = __shfl_xor(ai, tm);
        bool take = (l & cm) != 0;
        ar = take ? pr : ar;
        ai = take ? pi : ai;
    }

    // Phase 6: RX(qw[4][i], i)
    #pragma unroll
    for (int i = 0; i < 6; ++i) {
        const int mask = 1 << (5 - i);
        float th = 0.5f * qw[4 * 6 + i];
        float c = cosf(th), sn = sinf(th);
        float pr = __shfl_xor(ar, mask);
        float pi = __shfl_xor(ai, mask);
        float nr = c * ar + sn * pi;
        float ni = c * ai - sn * pr;
        ar = nr; ai = ni;
    }

    U2[(l * 64 + b) * 2 + 0] = ar;
    U2[(l * 64 + b) * 2 + 1] = ai;
}

// ---------------------------------------------------------------------------
// Kernel 2: fully fused per-sample pipeline. One thread per sample.
// ---------------------------------------------------------------------------
__global__ __launch_bounds__(256) void fused_main(
    const float* __restrict__ x,
    const float* __restrict__ W1, const float* __restrict__ b1,
    const float* __restrict__ W2, const float* __restrict__ b2,
    const float* __restrict__ W3, const float* __restrict__ b3,
    const float* __restrict__ W4, const float* __restrict__ b4,
    const float* __restrict__ W5, const float* __restrict__ b5,
    const float* __restrict__ U2,
    float* __restrict__ out, int B)
{
    const int s = blockIdx.x * blockDim.x + threadIdx.x;
    if (s >= B) return;

    // ---- Layer 1: h1 = relu(x[s,:] @ W1 + b1)   (128 -> 32)
    float h1[32];
    #pragma unroll
    for (int o = 0; o < 32; ++o) h1[o] = b1[o];
    const float4* x4 = reinterpret_cast<const float4*>(x + (size_t)s * 128);
    for (int j4 = 0; j4 < 32; ++j4) {
        float4 xv = x4[j4];
        const float* w = W1 + j4 * 4 * 32;   // row-major (128,32)
        #pragma unroll
        for (int o = 0; o < 32; ++o) h1[o] = fmaf(xv.x, w[o], h1[o]);
        #pragma unroll
        for (int o = 0; o < 32; ++o) h1[o] = fmaf(xv.y, w[32 + o], h1[o]);
        #pragma unroll
        for (int o = 0; o < 32; ++o) h1[o] = fmaf(xv.z, w[64 + o], h1[o]);
        #pragma unroll
        for (int o = 0; o < 32; ++o) h1[o] = fmaf(xv.w, w[96 + o], h1[o]);
    }
    #pragma unroll
    for (int o = 0; o < 32; ++o) h1[o] = fmaxf(h1[o], 0.0f);

    // ---- Layer 2: h2 = relu(h1 @ W2 + b2)   (32 -> 16)
    float h2[16];
    #pragma unroll
    for (int o = 0; o < 16; ++o) h2[o] = b2[o];
    #pragma unroll
    for (int j = 0; j < 32; ++j) {
        #pragma unroll
        for (int o = 0; o < 16; ++o) h2[o] = fmaf(h1[j], W2[j * 16 + o], h2[o]);
    }
    #pragma unroll
    for (int o = 0; o < 16; ++o) h2[o] = fmaxf(h2[o], 0.0f);

    // ---- Layer 3: angles = clip(tanh(h2 @ W3 + b3),-1,1)*pi ; half-angle cos/sin
    float cq[6], sq[6];
    #pragma unroll
    for (int q = 0; q < 6; ++q) {
        float t = b3[q];
        #pragma unroll
        for (int j = 0; j < 16; ++j) t = fmaf(h2[j], W3[j * 6 + q], t);
        t = tanhf(t);
        t = fminf(1.0f, fmaxf(-1.0f, t));
        float half = t * (0.5f * PI_F);
        sq[q] = sinf(half);
        cq[q] = cosf(half);
    }

    // ---- psi0[k] = prod_i (bit_{5-i}(k) ? sin : cos)  via doubling tree
    float psi[64];
    psi[0] = cq[5]; psi[1] = sq[5];
    #pragma unroll
    for (int q = 4; q >= 0; --q) {
        const int sz = 1 << (5 - q);
        #pragma unroll
        for (int r = 0; r < sz; ++r) {
            float v = psi[r];
            psi[r + sz] = sq[q] * v;
            psi[r]      = cq[q] * v;
        }
    }

    // ---- phi = U * psi0 ; q_out[q] = sum_k sign(q,k) * |phi_k|^2
    float acc0 = 0.f, acc1 = 0.f, acc2 = 0.f, acc3 = 0.f, acc4 = 0.f, acc5 = 0.f;
    #pragma unroll 2
    for (int k = 0; k < 64; ++k) {
        const float* u = U2 + k * 128;   // uniform address -> scalar loads
        float re = 0.0f, im = 0.0f;
        #pragma unroll
        for (int j = 0; j < 64; ++j) {
            re = fmaf(u[2 * j],     psi[j], re);
            im = fmaf(u[2 * j + 1], psi[j], im);
        }
        float p  = re * re + im * im;
        float pn = -p;
        acc0 += (k & 32) ? pn : p;
        acc1 += (k & 16) ? pn : p;
        acc2 += (k & 8)  ? pn : p;
        acc3 += (k & 4)  ? pn : p;
        acc4 += (k & 2)  ? pn : p;
        acc5 += (k & 1)  ? pn : p;
    }
    float qv[6] = {acc0, acc1, acc2, acc3, acc4, acc5};

    // ---- Layer 4: h4 = relu(q_out @ W4 + b4)   (6 -> 16)
    float h4[16];
    #pragma unroll
    for (int o = 0; o < 16; ++o) h4[o] = b4[o];
    #pragma unroll
    for (int q = 0; q < 6; ++q) {
        #pragma unroll
        for (int o = 0; o < 16; ++o) h4[o] = fmaf(qv[q], W4[q * 16 + o], h4[o]);
    }
    #pragma unroll
    for (int o = 0; o < 16; ++o) h4[o] = fmaxf(h4[o], 0.0f);

    // ---- Layer 5: out = h4 @ W5 + b5   (16 -> 20)
    float o5[20];
    #pragma unroll
    for (int o = 0; o < 20; ++o) {
        float t = b5[o];
        #pragma unroll
        for (int j = 0; j < 16; ++j) t = fmaf(h4[j], W5[j * 20 + o], t);
        o5[o] = t;
    }
    float4* outv = reinterpret_cast<float4*>(out + (size_t)s * 20);
    #pragma unroll
    for (int i = 0; i < 5; ++i)
        outv[i] = make_float4(o5[4 * i], o5[4 * i + 1], o5[4 * i + 2], o5[4 * i + 3]);
}

// ---------------------------------------------------------------------------
extern "C" void kernel_launch(void* const* d_in, const int* in_sizes, int n_in,
                              void* d_out, int out_size, void* d_ws, size_t ws_size,
                              hipStream_t stream) {
    const float* x  = (const float*)d_in[0];
    const float* W1 = (const float*)d_in[1];
    const float* b1 = (const float*)d_in[2];
    const float* W2 = (const float*)d_in[3];
    const float* b2 = (const float*)d_in[4];
    const float* W3 = (const float*)d_in[5];
    const float* b3 = (const float*)d_in[6];
    const float* qw = (const float*)d_in[7];
    const float* W4 = (const float*)d_in[8];
    const float* b4 = (const float*)d_in[9];
    const float* W5 = (const float*)d_in[10];
    const float* b5 = (const float*)d_in[11];
    float* out = (float*)d_out;
    float* U2  = (float*)d_ws;   // 64*64*2 floats = 32 KB

    const int B = in_sizes[0] / 128;

    build_u<<<64, 64, 0, stream>>>(qw, U2);
    fused_main<<<(B + 255) / 256, 256, 0, stream>>>(
        x, W1, b1, W2, b2, W3, b3, W4, b4, W5, b5, U2, out, B);
}